// Round 7
// baseline (219.707 us; speedup 1.0000x reference)
//
#include <hip/hip_runtime.h>
#include <hip/hip_bf16.h>
#include <math.h>

// KAN layer: out = GELU( einsum('bik,ikj->bj', x^k, W) + bias ),
//   B=4096, D=1024, K=5, U=1024.
//
// Round 7: R6 hybrid (B via LDS-DMA dbuf, A-power-frags built in registers)
// scaled for latency hiding:
//  - 64x64 tiles -> grid (16,64) = 1024 blocks = 4+ blocks/CU (R2-R6 showed
//    blocks/CU is the dominant variable: barrier drains + L2 latency need
//    co-resident blocks to cover them).
//  - x prefetch 2-deep (it+2): ~2 iters (>=400 cyc) of L2-latency cover.
//  - bias fold partials reduced 32 -> 8 (prep blocks cover 128 i each).

#define B_DIM 4096
#define D_DIM 1024
#define U_DIM 1024
#define KT2 4096            // GEMM K after dropping k=0 plane
#define NKB 128             // 32-wide k-blocks

typedef unsigned short ushort_t;
typedef __attribute__((ext_vector_type(8))) short bf16x8;   // MFMA A/B frag
typedef __attribute__((ext_vector_type(4))) float f32x4;    // MFMA C/D frag

__device__ __forceinline__ ushort_t f2bf(float f) {   // RNE (prep kernel)
  union { float f; unsigned int u; } v;
  v.f = f;
  unsigned int r = v.u + 0x7FFFu + ((v.u >> 16) & 1u);
  return (ushort_t)(r >> 16);
}

__device__ __forceinline__ void load_lds16(const ushort_t* g, ushort_t* l) {
  __builtin_amdgcn_global_load_lds(
      (const __attribute__((address_space(1))) ushort_t*)g,
      (__attribute__((address_space(3))) ushort_t*)l, 16, 0, 0);
}

__device__ __forceinline__ float gelu_exact(float v) {
  return 0.5f * v * (1.0f + erff(v * 0.70710678118654752f));
}

__device__ __forceinline__ unsigned int fbits(float f) {
  union { float f; unsigned int u; } v; v.f = f; return v.u;
}

// A-frag: 8 bf16 = {xa,xa^2,xa^3,xa^4, xb,xb^2,xb^3,xb^4}; v_perm_b32 packs
// two f32 high halves per dword (truncation, |err|<=ulp).
__device__ __forceinline__ bf16x8 build_afrag(float xa, float xb) {
  const float a2 = xa * xa, b2 = xb * xb;
  const float a3 = a2 * xa, a4 = a2 * a2;
  const float b3 = b2 * xb, b4 = b2 * b2;
  union { bf16x8 v; unsigned int d[4]; } r;
  r.d[0] = __builtin_amdgcn_perm(fbits(a2), fbits(xa), 0x07060302u);
  r.d[1] = __builtin_amdgcn_perm(fbits(a4), fbits(a3), 0x07060302u);
  r.d[2] = __builtin_amdgcn_perm(fbits(b2), fbits(xb), 0x07060302u);
  r.d[3] = __builtin_amdgcn_perm(fbits(b4), fbits(b3), 0x07060302u);
  return r.v;
}

// packed addr (ushorts) of (row=j, k): ((j>>4)*NKB + (k>>5))*512
//                                       + (((k>>3)&3)*16 + (j&15))*8 + (k&7)

// ---------------- prep: pack W planes 1..4 + 8-way partial sums of plane 0 ----------------
// grid (8, 64): block (bx, n16) covers i in [bx*128, +128), j in [n16*16, +16).
__global__ __launch_bounds__(256) void w_pack_fold_kernel(
    const float* __restrict__ W, ushort_t* __restrict__ Bp, float* __restrict__ part) {
  const int t    = threadIdx.x;
  const int wave = t >> 6;
  const int lane = t & 63;
  const int bx   = blockIdx.x;                // 0..7
  const int n16  = blockIdx.y;                // 0..63
  // ---- pack: each wave packs 4 units (kblk = bx*16 + wave*4 + s) ----
#pragma unroll
  for (int s = 0; s < 4; ++s) {
    const int kblk = bx * 16 + wave * 4 + s;  // 0..127
    const int jj   = lane & 15;
    const int ko   = lane >> 4;
    const int j    = n16 * 16 + jj;
    const int i0   = kblk * 8 + ko * 2;
    ushort_t o[8];
#pragma unroll
    for (int t2 = 0; t2 < 2; ++t2) {
      const int i = i0 + t2;
#pragma unroll
      for (int e = 0; e < 4; ++e) {
        const int r = i * 5 + e + 1;          // skip k=0 plane
        o[t2 * 4 + e] = f2bf(W[(size_t)r * U_DIM + j]);
      }
    }
    *(uint4*)(Bp + ((size_t)n16 * NKB + kblk) * 512 + lane * 8) = *(const uint4*)o;
  }
  // ---- fold: partial sum over this block's 128 i of W[i,0,j] ----
  __shared__ float red[16][17];
  {
    const int jj = t & 15;
    const int ii = t >> 4;                    // 0..15
    const int j  = n16 * 16 + jj;
    float s = 0.0f;
#pragma unroll
    for (int g = 0; g < 8; ++g) {
      const int i = bx * 128 + ii + g * 16;
      s += W[(size_t)(i * 5) * U_DIM + j];
    }
    red[ii][jj] = s;
  }
  __syncthreads();
  if (t < 16) {
    float s = 0.0f;
#pragma unroll
    for (int ii = 0; ii < 16; ++ii) s += red[ii][t];
    part[(size_t)bx * U_DIM + n16 * 16 + t] = s;
  }
}

// ---------------- main GEMM: 64x64 tile, B via dbuf LDS DMA, A in regs ----------------
// 4 waves: wave tile 32x32 (2x2 of 16x16x32). BK=64 (2 k32-blocks/iter), 64 iters.
__global__ __launch_bounds__(256, 4) void gemm_kernel(
    const float* __restrict__ x, const ushort_t* __restrict__ Bp,
    const float* __restrict__ bias, const float* __restrict__ part,
    float* __restrict__ C) {
  __shared__ ushort_t lds[2][8 * 512];    // 2 x 8 KB; unit u = kl*4 + nloc

  const int tid  = threadIdx.x;
  const int wave = tid >> 6;
  const int lane = tid & 63;
  const int wm   = wave >> 1;             // 0..1 : 32-row half
  const int wn   = wave & 1;              // 0..1 : 32-col half
  const int tileN = blockIdx.x * 64;      // 16 n-tiles (XCD round-robin)
  const int tileM = blockIdx.y * 64;      // 64 m-tiles

  // DMA staging: wave stages units u = s*4 + wave (s=0,1): nloc=wave, kloc=s.
  // kblk advances 2/iter -> +1024 ushorts per iter.
  const ushort_t* gsrc[2];
  int ldst[2];
#pragma unroll
  for (int s = 0; s < 2; ++s) {
    gsrc[s] = Bp + ((size_t)((tileN >> 4) + wave) * NKB + s) * 512 + lane * 8;
    ldst[s] = (s * 4 + wave) * 512 + lane * 8;
  }

  // x pointers: frag mf covers rows tileM + wm*32 + mf*16 + (lane&15);
  // i offset per (it, kl): it*16 + kl*8 + (lane>>4)*2.
  const float* xptr[2];
#pragma unroll
  for (int mf = 0; mf < 2; ++mf)
    xptr[mf] = x + (size_t)(tileM + wm * 32 + mf * 16 + (lane & 15)) * D_DIM
                 + (lane >> 4) * 2;

  f32x4 acc[2][2];
  const f32x4 zero = {0.0f, 0.0f, 0.0f, 0.0f};
#pragma unroll
  for (int mf = 0; mf < 2; ++mf)
#pragma unroll
    for (int nf = 0; nf < 2; ++nf) acc[mf][nf] = zero;

#define STAGE(bb, it)                                                   \
  do {                                                                  \
    _Pragma("unroll")                                                   \
    for (int s = 0; s < 2; ++s)                                         \
      load_lds16(gsrc[s] + (size_t)(it) * 1024, &lds[bb][ldst[s]]);     \
  } while (0)

  // 2-deep x pipeline: xc = it, xn1 = it+1, xn2 = it+2
  float2 xc[2][2], xn1[2][2], xn2[2][2];
#pragma unroll
  for (int kl = 0; kl < 2; ++kl)
#pragma unroll
    for (int mf = 0; mf < 2; ++mf) {
      xc[kl][mf]  = *(const float2*)(xptr[mf] + kl * 8);
      xn1[kl][mf] = *(const float2*)(xptr[mf] + 16 + kl * 8);
    }

  STAGE(0, 0);
  __syncthreads();   // drain iter-0 DMA

  for (int it = 0; it < 64; ++it) {
    const int cur = it & 1;
    if (it + 1 < 64) STAGE(cur ^ 1, it + 1);   // in flight across this compute
    if (it + 2 < 64) {
#pragma unroll
      for (int kl = 0; kl < 2; ++kl)
#pragma unroll
        for (int mf = 0; mf < 2; ++mf)
          xn2[kl][mf] = *(const float2*)(xptr[mf] + (size_t)(it + 2) * 16 + kl * 8);
    }

#pragma unroll
    for (int kl = 0; kl < 2; ++kl) {
      bf16x8 a[2], b[2];
#pragma unroll
      for (int mf = 0; mf < 2; ++mf)
        a[mf] = build_afrag(xc[kl][mf].x, xc[kl][mf].y);
#pragma unroll
      for (int nf = 0; nf < 2; ++nf)
        b[nf] = *(const bf16x8*)&lds[cur][(kl * 4 + wn * 2 + nf) * 512 + lane * 8];
#pragma unroll
      for (int mf = 0; mf < 2; ++mf)
#pragma unroll
        for (int nf = 0; nf < 2; ++nf)
          acc[mf][nf] = __builtin_amdgcn_mfma_f32_16x16x32_bf16(a[mf], b[nf], acc[mf][nf], 0, 0, 0);
    }

#pragma unroll
    for (int kl = 0; kl < 2; ++kl)
#pragma unroll
      for (int mf = 0; mf < 2; ++mf) {
        xc[kl][mf]  = xn1[kl][mf];
        xn1[kl][mf] = xn2[kl][mf];
      }

    __syncthreads();   // releases cur for overwrite; drains next-iter DMA
  }
#undef STAGE

  // epilogue: C/D map: col = lane&15, row = (lane>>4)*4 + reg
  const int crow0 = tileM + wm * 32 + (lane >> 4) * 4;
  const int ccol0 = tileN + wn * 32 + (lane & 15);
#pragma unroll
  for (int nf = 0; nf < 2; ++nf) {
    const int col = ccol0 + nf * 16;
    float bv = bias[col];
#pragma unroll
    for (int g = 0; g < 8; ++g) bv += part[(size_t)g * U_DIM + col];
#pragma unroll
    for (int mf = 0; mf < 2; ++mf) {
#pragma unroll
      for (int r = 0; r < 4; ++r) {
        const int row = crow0 + mf * 16 + r;
        C[(size_t)row * U_DIM + col] = gelu_exact(acc[mf][nf][r] + bv);
      }
    }
  }
}

// ---------------- fallback (ws too small): fp32, no workspace ----------------
__global__ void fallback_kernel(const float* __restrict__ x, const float* __restrict__ W,
                                const float* __restrict__ bias, float* __restrict__ out) {
  int j  = blockIdx.x * 256 + threadIdx.x;
  int b0 = blockIdx.y * 16;
  float acc[16];
#pragma unroll
  for (int t = 0; t < 16; ++t) acc[t] = 0.0f;
  for (int i = 0; i < D_DIM; ++i) {
    const float* wr = W + (size_t)i * 5 * U_DIM + j;
    float w0 = wr[0 * U_DIM], w1 = wr[1 * U_DIM], w2 = wr[2 * U_DIM];
    float w3 = wr[3 * U_DIM], w4 = wr[4 * U_DIM];
#pragma unroll
    for (int t = 0; t < 16; ++t) {
      float xv = x[(size_t)(b0 + t) * D_DIM + i];
      float x2 = xv * xv;
      acc[t] += w0 + xv * w1 + x2 * w2 + x2 * xv * w3 + x2 * x2 * w4;
    }
  }
  float bv = bias[j];
#pragma unroll
  for (int t = 0; t < 16; ++t)
    out[(size_t)(b0 + t) * U_DIM + j] = gelu_exact(acc[t] + bv);
}

extern "C" void kernel_launch(void* const* d_in, const int* in_sizes, int n_in,
                              void* d_out, int out_size, void* d_ws, size_t ws_size,
                              hipStream_t stream) {
  const float* x    = (const float*)d_in[0];   // (4096, 1024)
  const float* W    = (const float*)d_in[1];   // (1024, 5, 1024), row r = i*5+k
  const float* bias = (const float*)d_in[2];   // (1024,)
  float* out = (float*)d_out;                  // (4096, 1024) fp32

  const size_t szB = (size_t)U_DIM * KT2 * sizeof(ushort_t);   // 8.39 MB
  const size_t szP = (size_t)8 * U_DIM * sizeof(float);        // 32 KB

  if (ws_size >= szB + szP) {
    ushort_t* Bp   = (ushort_t*)d_ws;
    float*    part = (float*)((char*)d_ws + szB);
    w_pack_fold_kernel<<<dim3(8, U_DIM / 16), 256, 0, stream>>>(W, Bp, part);
    gemm_kernel<<<dim3(U_DIM / 64, B_DIM / 64), 256, 0, stream>>>(x, Bp, bias, part, out);
  } else {
    fallback_kernel<<<dim3(U_DIM / 256, B_DIM / 16), 256, 0, stream>>>(x, W, bias, out);
  }
}

// Round 8
// 150.434 us; speedup vs baseline: 1.4605x; 1.4605x over previous
//
#include <hip/hip_runtime.h>
#include <hip/hip_bf16.h>
#include <math.h>

// KAN layer: out = GELU( einsum('bik,ikj->bj', x^k, W) + bias ),
//   B=4096, D=1024, K=5, U=1024.
//
// Round 8: gemm = R3's measured-52us kernel verbatim (A+B pre-packed in MFMA
// unit order, DMA global->LDS dbuf, 64x128 tile, BK=64, 512 blocks); preps
// rewritten for coalescing:
//  - basis_pack: float4 x loads (64B/row/instr), direct uint4 packed stores.
//  - w_pack_fold: LDS-staged; reads W in 128B dense lines exactly once;
//    packs B units + folds k=0 plane into part[16][1024] in one kernel.
//  - gemm epilogue sums the 16 partials + bias (no fold_final launch).

#define B_DIM 4096
#define D_DIM 1024
#define U_DIM 1024
#define KT2 4096            // GEMM K after dropping k=0 plane (k = i*4 + e-1)
#define NKB 128             // 32-wide k-blocks

typedef unsigned short ushort_t;
typedef __attribute__((ext_vector_type(8))) short bf16x8;   // MFMA A/B frag
typedef __attribute__((ext_vector_type(4))) float f32x4;    // MFMA C/D frag

__device__ __forceinline__ ushort_t f2bf(float f) {   // RNE
  union { float f; unsigned int u; } v;
  v.f = f;
  unsigned int r = v.u + 0x7FFFu + ((v.u >> 16) & 1u);
  return (ushort_t)(r >> 16);
}

__device__ __forceinline__ void load_lds16(const ushort_t* g, ushort_t* l) {
  __builtin_amdgcn_global_load_lds(
      (const __attribute__((address_space(1))) ushort_t*)g,
      (__attribute__((address_space(3))) ushort_t*)l, 16, 0, 0);
}

__device__ __forceinline__ float gelu_exact(float v) {
  return 0.5f * v * (1.0f + erff(v * 0.70710678118654752f));
}

// packed addr (ushorts) of (row, k): ((row>>4)*NKB + (k>>5))*512
//                                     + (((k>>3)&3)*16 + (row&15))*8 + (k&7)

// ---------------- prep 1: x -> A_packed (powers 1..4) ----------------
// grid (4, 256). Block (bx, m16) covers i in [bx*256, +256) for 16 rows.
// thread: m = tid&15, q = tid>>4; per iter: one float4 x load (4 i),
// two uint4 packed stores (2 pair-octets).
__global__ __launch_bounds__(256) void basis_pack_kernel(
    const float* __restrict__ x, ushort_t* __restrict__ Ap) {
  const int tid = threadIdx.x;
  const int m   = tid & 15;
  const int q   = tid >> 4;              // 0..15
  const int m16 = blockIdx.y;            // 0..255
  const int row = m16 * 16 + m;
  const float* xrow = x + (size_t)row * D_DIM;

#pragma unroll
  for (int it = 0; it < 4; ++it) {
    const int it_g = blockIdx.x * 4 + it;     // 0..15
    const int i0   = it_g * 64 + q * 4;       // multiple of 4
    const float4 f = *(const float4*)(xrow + i0);

    const int kb    = i0 >> 3;                // unit k-block
    const int octA  = (q & 1) * 2;            // octet of pair (i0, i0+1)
    ushort_t oA[8], oB[8];
    {
      const float a = f.x, b = f.y;
      const float a2 = a * a, b2 = b * b;
      oA[0] = f2bf(a);  oA[1] = f2bf(a2); oA[2] = f2bf(a2 * a); oA[3] = f2bf(a2 * a2);
      oA[4] = f2bf(b);  oA[5] = f2bf(b2); oA[6] = f2bf(b2 * b); oA[7] = f2bf(b2 * b2);
    }
    {
      const float a = f.z, b = f.w;
      const float a2 = a * a, b2 = b * b;
      oB[0] = f2bf(a);  oB[1] = f2bf(a2); oB[2] = f2bf(a2 * a); oB[3] = f2bf(a2 * a2);
      oB[4] = f2bf(b);  oB[5] = f2bf(b2); oB[6] = f2bf(b2 * b); oB[7] = f2bf(b2 * b2);
    }
    ushort_t* ub = Ap + ((size_t)m16 * NKB + kb) * 512;
    *(uint4*)(ub + (octA * 16 + m) * 8)       = *(const uint4*)oA;
    *(uint4*)(ub + ((octA + 1) * 16 + m) * 8) = *(const uint4*)oB;
  }
}

// ---------------- prep 2: W -> B_packed (planes 1..4) + fold plane 0 ----------------
// grid (32, 16). Block (bj, bi): j in [bj*32,+32), i in [bi*64,+64).
// Read: 40 iters x 8 rows, each 32-lane half-wave reads one 128B row-chunk
// (fully dense lines). e>=1 -> LDS bf16 (pitch 34, conflict-free);
// e==0 -> register fold, reduced to part[bi][j].
__global__ __launch_bounds__(256) void w_pack_fold_kernel(
    const float* __restrict__ W, ushort_t* __restrict__ Bp, float* __restrict__ part) {
  __shared__ ushort_t st[256 * 34];   // 17 KB, element (kpos, col) at kpos*34+col
  __shared__ float red[8][32];

  const int tid = threadIdx.x;
  const int bj  = blockIdx.x;          // 0..31
  const int bi  = blockIdx.y;          // 0..15
  const int j0  = bj * 32;
  const int col = tid & 31;            // j offset
  const int rr  = tid >> 5;            // 0..7 (row offset within iter)
  const float* wbase = W + (size_t)(bi * 64) * 5 * U_DIM + j0;

  float facc = 0.0f;
#pragma unroll 8
  for (int t = 0; t < 40; ++t) {
    const int r_loc = t * 8 + rr;             // 0..319
    const float v = wbase[(size_t)r_loc * U_DIM + col];
    const int i_loc = r_loc / 5;
    const int e     = r_loc - i_loc * 5;
    if (e == 0) {
      facc += v;
    } else {
      st[(i_loc * 4 + e - 1) * 34 + col] = f2bf(v);
    }
  }
  red[rr][col] = facc;
  __syncthreads();

  // fold reduce: 32 threads
  if (tid < 32) {
    float s = 0.0f;
#pragma unroll
    for (int g = 0; g < 8; ++g) s += red[g][tid];
    part[(size_t)bi * U_DIM + j0 + tid] = s;
  }

  // pack: 16 units (2 n16loc x 8 kbloc); wave w handles units w*4..w*4+3
  const int wave = tid >> 6;
  const int lane = tid & 63;
  const int jj   = lane & 15;
  const int ko   = lane >> 4;
#pragma unroll
  for (int s = 0; s < 4; ++s) {
    const int u      = wave * 4 + s;      // 0..15
    const int n16loc = u & 1;
    const int kbloc  = u >> 1;            // 0..7
    const int j_loc  = n16loc * 16 + jj;
    const int i_loc0 = kbloc * 8 + ko * 2;
    ushort_t o[8];
#pragma unroll
    for (int t2 = 0; t2 < 2; ++t2)
#pragma unroll
      for (int e = 0; e < 4; ++e)
        o[t2 * 4 + e] = st[((i_loc0 + t2) * 4 + e) * 34 + j_loc];
    const int n16 = bj * 2 + n16loc;
    const int kb  = bi * 8 + kbloc;
    *(uint4*)(Bp + ((size_t)n16 * NKB + kb) * 512 + lane * 8) = *(const uint4*)o;
  }
}

// ---------------- main GEMM (R3 verbatim): 64x128, BK=64, dbuf DMA ----------------
// buffer: unit u = ku*12 + r; r 0..3 = A m16, r 4..11 = B n16. 2 x 24 KB.
__global__ __launch_bounds__(256) void gemm_kernel(
    const ushort_t* __restrict__ Ap, const ushort_t* __restrict__ Bp,
    const float* __restrict__ bias, const float* __restrict__ part,
    float* __restrict__ C) {
  __shared__ ushort_t lds[2][24 * 512];

  const int tid  = threadIdx.x;
  const int wave = tid >> 6;
  const int lane = tid & 63;
  const int wm   = wave >> 1;
  const int wn   = wave & 1;
  const int m16b = blockIdx.y * 4;        // tile M=64
  const int n16b = blockIdx.x * 8;        // tile N=128

  const ushort_t* gsrc[6];
  int ldst[6];
#pragma unroll
  for (int s = 0; s < 6; ++s) {
    const int u  = s * 4 + wave;
    const int ku = (u >= 12) ? 1 : 0;
    const int r  = u - ku * 12;
    const ushort_t* base = (r < 4)
        ? Ap + ((size_t)(m16b + r) * NKB) * 512
        : Bp + ((size_t)(n16b + (r - 4)) * NKB) * 512;
    gsrc[s] = base + (size_t)ku * 512 + lane * 8;
    ldst[s] = u * 512 + lane * 8;
  }

  f32x4 acc[2][4];
  const f32x4 zero = {0.0f, 0.0f, 0.0f, 0.0f};
#pragma unroll
  for (int mf = 0; mf < 2; ++mf)
#pragma unroll
    for (int nf = 0; nf < 4; ++nf) acc[mf][nf] = zero;

#define STAGE(bb, it)                                                   \
  do {                                                                  \
    _Pragma("unroll")                                                   \
    for (int s = 0; s < 6; ++s)                                         \
      load_lds16(gsrc[s] + (size_t)(it) * 1024, &lds[bb][ldst[s]]);     \
  } while (0)

  STAGE(0, 0);
  __syncthreads();

  for (int it = 0; it < 64; ++it) {
    const int cur = it & 1;
    if (it + 1 < 64) STAGE(cur ^ 1, it + 1);

#pragma unroll
    for (int ku = 0; ku < 2; ++ku) {
      bf16x8 a[2], b[4];
#pragma unroll
      for (int mf = 0; mf < 2; ++mf)
        a[mf] = *(const bf16x8*)&lds[cur][(ku * 12 + wm * 2 + mf) * 512 + lane * 8];
#pragma unroll
      for (int nf = 0; nf < 4; ++nf)
        b[nf] = *(const bf16x8*)&lds[cur][(ku * 12 + 4 + wn * 4 + nf) * 512 + lane * 8];
#pragma unroll
      for (int mf = 0; mf < 2; ++mf)
#pragma unroll
        for (int nf = 0; nf < 4; ++nf)
          acc[mf][nf] = __builtin_amdgcn_mfma_f32_16x16x32_bf16(a[mf], b[nf], acc[mf][nf], 0, 0, 0);
    }
    __syncthreads();
  }
#undef STAGE

  // epilogue: C/D map: col = lane&15, row = (lane>>4)*4 + reg
  const int crow0 = m16b * 16 + wm * 32 + (lane >> 4) * 4;
  const int ccol0 = n16b * 16 + wn * 64 + (lane & 15);
#pragma unroll
  for (int nf = 0; nf < 4; ++nf) {
    const int col = ccol0 + nf * 16;
    float bv = bias[col];
#pragma unroll
    for (int g = 0; g < 16; ++g) bv += part[(size_t)g * U_DIM + col];
#pragma unroll
    for (int mf = 0; mf < 2; ++mf) {
#pragma unroll
      for (int r = 0; r < 4; ++r) {
        const int row = crow0 + mf * 16 + r;
        C[(size_t)row * U_DIM + col] = gelu_exact(acc[mf][nf][r] + bv);
      }
    }
  }
}

// ---------------- fallback (ws too small): fp32, no workspace ----------------
__global__ void fallback_kernel(const float* __restrict__ x, const float* __restrict__ W,
                                const float* __restrict__ bias, float* __restrict__ out) {
  int j  = blockIdx.x * 256 + threadIdx.x;
  int b0 = blockIdx.y * 16;
  float acc[16];
#pragma unroll
  for (int t = 0; t < 16; ++t) acc[t] = 0.0f;
  for (int i = 0; i < D_DIM; ++i) {
    const float* wr = W + (size_t)i * 5 * U_DIM + j;
    float w0 = wr[0 * U_DIM], w1 = wr[1 * U_DIM], w2 = wr[2 * U_DIM];
    float w3 = wr[3 * U_DIM], w4 = wr[4 * U_DIM];
#pragma unroll
    for (int t = 0; t < 16; ++t) {
      float xv = x[(size_t)(b0 + t) * D_DIM + i];
      float x2 = xv * xv;
      acc[t] += w0 + xv * w1 + x2 * w2 + x2 * xv * w3 + x2 * x2 * w4;
    }
  }
  float bv = bias[j];
#pragma unroll
  for (int t = 0; t < 16; ++t)
    out[(size_t)(b0 + t) * U_DIM + j] = gelu_exact(acc[t] + bv);
}

extern "C" void kernel_launch(void* const* d_in, const int* in_sizes, int n_in,
                              void* d_out, int out_size, void* d_ws, size_t ws_size,
                              hipStream_t stream) {
  const float* x    = (const float*)d_in[0];   // (4096, 1024)
  const float* W    = (const float*)d_in[1];   // (1024, 5, 1024), row r = i*5+k
  const float* bias = (const float*)d_in[2];   // (1024,)
  float* out = (float*)d_out;                  // (4096, 1024) fp32

  const size_t szA = (size_t)B_DIM * KT2 * sizeof(ushort_t);   // 33.55 MB
  const size_t szB = (size_t)U_DIM * KT2 * sizeof(ushort_t);   //  8.39 MB
  const size_t szP = (size_t)16 * U_DIM * sizeof(float);       //  64 KB

  if (ws_size >= szA + szB + szP) {
    ushort_t* Ap   = (ushort_t*)d_ws;
    ushort_t* Bp   = (ushort_t*)((char*)d_ws + szA);
    float*    part = (float*)((char*)d_ws + szA + szB);
    basis_pack_kernel<<<dim3(4, B_DIM / 16), 256, 0, stream>>>(x, Ap);
    w_pack_fold_kernel<<<dim3(32, 16), 256, 0, stream>>>(W, Bp, part);
    gemm_kernel<<<dim3(U_DIM / 128, B_DIM / 64), 256, 0, stream>>>(Ap, Bp, bias, part, out);
  } else {
    fallback_kernel<<<dim3(U_DIM / 256, B_DIM / 16), 256, 0, stream>>>(x, W, bias, out);
  }
}